// Round 1
// baseline (385.168 us; speedup 1.0000x reference)
//
#include <hip/hip_runtime.h>

// VQ-VAE vector quantization forward:
//   inputs [32,256,32,32] f32, weight [1024,256] f32
//   outputs: quantized_st [32,256,32,32] f32, vq_loss scalar, usage [1024] (as f32 counts)
//
// d_out layout: [0,8388608) quantized | [8388608] loss | [8388609,+1024) usage

#define DDIM 256
#define KCODES 1024
#define HWSZ 1024
#define TN 64
#define TK 128
#define XPAD 260   // 64 rows x 260 floats (pad 4 -> 16B-aligned rows, 2-way max conflicts w/ row permute)
#define WPAD 68    // 128 rows x 68 floats
#define SMEM_FLOATS (TN * XPAD + TK * WPAD)
#define SMEM_BYTES (SMEM_FLOATS * 4)
#define NQ 8388608

extern "C" __global__ __launch_bounds__(256) void init_kernel(float* __restrict__ usage) {
    int t = blockIdx.x * 256 + threadIdx.x;
    if (t < KCODES) usage[t] = 0.0f;
}

// one wave per code row: wsq[k] = sum_d w[k][d]^2
extern "C" __global__ __launch_bounds__(256) void wsq_kernel(const float* __restrict__ w,
                                                             float* __restrict__ wsq) {
    int wave = threadIdx.x >> 6;
    int lane = threadIdx.x & 63;
    int k = blockIdx.x * 4 + wave;
    float4 v = *reinterpret_cast<const float4*>(w + (size_t)k * DDIM + lane * 4);
    float s = v.x * v.x + v.y * v.y + v.z * v.z + v.w * v.w;
    #pragma unroll
    for (int off = 32; off >= 1; off >>= 1) s += __shfl_xor(s, off, 64);
    if (lane == 0) wsq[k] = s;
}

// main: 512 blocks x 256 threads; each block owns 64 points (one batch b, 64 consecutive hw)
extern "C" __global__ __launch_bounds__(256) void vq_main(const float* __restrict__ inp,
                                                          const float* __restrict__ w,
                                                          const float* __restrict__ wsq,
                                                          float* __restrict__ outq,
                                                          float* __restrict__ usage,
                                                          float* __restrict__ partial) {
    extern __shared__ float smem[];
    float* xs = smem;                // [64][260], row-permuted: x-point n stored at row (n&3)*16 + (n>>2)
    float* wt = smem + TN * XPAD;    // [128][68], row-permuted: code kl stored at row (kl&7)*16 + (kl>>3)

    const int tid = threadIdx.x;
    const int blk = blockIdx.x;
    const int b = blk >> 4;
    const int hw0 = (blk & 15) * 64;
    const float* xin = inp + (size_t)b * DDIM * HWSZ + hw0;

    // ---- stage x tile: 64 points x 256 dims (coalesced f4 global reads) ----
    #pragma unroll
    for (int it = 0; it < 16; ++it) {
        int e4 = it * 256 + tid;         // 4096 float4
        int d = e4 >> 4;                 // 0..255
        int i4 = (e4 & 15) * 4;          // point base 0..60
        float4 v = *reinterpret_cast<const float4*>(xin + (size_t)d * HWSZ + i4);
        int rb = i4 >> 2;
        xs[(rb)*XPAD + d] = v.x;         // rho(i4+0) = 0*16 + rb
        xs[(16 + rb) * XPAD + d] = v.y;
        xs[(32 + rb) * XPAD + d] = v.z;
        xs[(48 + rb) * XPAD + d] = v.w;
    }

    const int ng = tid & 15;   // owns points n = 4*ng + i, i=0..3
    const int kg = tid >> 4;   // owns codes k = kt*128 + kg*8 + j, j=0..7

    float bval[4];
    int bidx[4];
    #pragma unroll
    for (int i = 0; i < 4; ++i) { bval[i] = 3.4e38f; bidx[i] = 0; }

    for (int kt = 0; kt < 8; ++kt) {
        float acc[4][8];
        #pragma unroll
        for (int i = 0; i < 4; ++i)
            #pragma unroll
            for (int j = 0; j < 8; ++j) acc[i][j] = 0.0f;

        for (int dc = 0; dc < 4; ++dc) {
            __syncthreads();
            // stage w slice: 128 codes x 64 dims
            #pragma unroll
            for (int it2 = 0; it2 < 8; ++it2) {
                int e4 = it2 * 256 + tid;    // 2048 float4
                int kl = e4 >> 4;
                int dq = e4 & 15;
                float4 v = *reinterpret_cast<const float4*>(
                    w + (size_t)(kt * TK + kl) * DDIM + dc * 64 + dq * 4);
                int pi = (kl & 7) * 16 + (kl >> 3);
                *reinterpret_cast<float4*>(wt + pi * WPAD + dq * 4) = v;
            }
            __syncthreads();

            const float* xb = xs + ng * XPAD + dc * 64;  // row i*16+ng
            const float* wb = wt + kg * WPAD;            // row j*16+kg
            #pragma unroll 4
            for (int dq = 0; dq < 16; ++dq) {
                float4 xv[4], wv[8];
                #pragma unroll
                for (int i = 0; i < 4; ++i)
                    xv[i] = *reinterpret_cast<const float4*>(xb + i * 16 * XPAD + dq * 4);
                #pragma unroll
                for (int j = 0; j < 8; ++j)
                    wv[j] = *reinterpret_cast<const float4*>(wb + j * 16 * WPAD + dq * 4);
                #pragma unroll
                for (int i = 0; i < 4; ++i)
                    #pragma unroll
                    for (int j = 0; j < 8; ++j) {
                        acc[i][j] += xv[i].x * wv[j].x;
                        acc[i][j] += xv[i].y * wv[j].y;
                        acc[i][j] += xv[i].z * wv[j].z;
                        acc[i][j] += xv[i].w * wv[j].w;
                    }
            }
        }
        // argmin epilogue for this k-tile: s = wsq[k] - 2*dot (||x||^2 irrelevant for argmin)
        #pragma unroll
        for (int j = 0; j < 8; ++j) {
            int k = kt * TK + kg * 8 + j;
            float q = wsq[k];
            #pragma unroll
            for (int i = 0; i < 4; ++i) {
                float s = q - 2.0f * acc[i][j];
                if (s < bval[i]) { bval[i] = s; bidx[i] = k; }  // k ascending per thread -> first-min kept
            }
        }
    }

    // ---- cross-thread argmin reduce per point (16 kg threads per n) ----
    __syncthreads();
    float* redv = wt;                     // [64][16]
    int* redi = (int*)(wt + 64 * 16);     // [64][16]
    #pragma unroll
    for (int i = 0; i < 4; ++i) {
        redv[(ng * 4 + i) * 16 + kg] = bval[i];
        redi[(ng * 4 + i) * 16 + kg] = bidx[i];
    }
    __syncthreads();
    __shared__ int best_s[TN];
    if (tid < 64) {
        float bv = redv[tid * 16];
        int bi = redi[tid * 16];
        #pragma unroll
        for (int g = 1; g < 16; ++g) {
            float v = redv[tid * 16 + g];
            int ix = redi[tid * 16 + g];
            if (v < bv || (v == bv && ix < bi)) { bv = v; bi = ix; }
        }
        best_s[tid] = bi;
        atomicAdd(usage + bi, 1.0f);   // integer-valued f32 adds: exact & order-independent
    }
    __syncthreads();

    // ---- gather codes, write output, accumulate loss ----
    float lsum = 0.0f;
    float* outb = outq + (size_t)b * DDIM * HWSZ + hw0;
    const int i = tid & 63;
    const int dhi = tid >> 6;
    const int xrow = ((i & 3) * 16 + (i >> 2)) * XPAD;
    for (int it = 0; it < 64; ++it) {
        int d = dhi + it * 4;
        float q = w[(size_t)best_s[i] * DDIM + d];
        float x = xs[xrow + d];
        outb[(size_t)d * HWSZ + i] = q;
        float df = q - x;
        lsum += df * df;
    }
    #pragma unroll
    for (int off = 32; off >= 1; off >>= 1) lsum += __shfl_xor(lsum, off, 64);
    __shared__ float wred[4];
    if ((tid & 63) == 0) wred[tid >> 6] = lsum;
    __syncthreads();
    if (tid == 0) partial[blk] = (wred[0] + wred[1]) + (wred[2] + wred[3]);
}

// deterministic final reduce of 512 block partials -> vq_loss
extern "C" __global__ __launch_bounds__(256) void final_kernel(const float* __restrict__ partial,
                                                               float* __restrict__ out_loss) {
    __shared__ float sm[256];
    int t = threadIdx.x;
    sm[t] = partial[t] + partial[t + 256];
    __syncthreads();
    #pragma unroll
    for (int off = 128; off >= 1; off >>= 1) {
        if (t < off) sm[t] += sm[t + off];
        __syncthreads();
    }
    if (t == 0) out_loss[0] = sm[0] * (1.25f / 8388608.0f);
}

extern "C" void kernel_launch(void* const* d_in, const int* in_sizes, int n_in,
                              void* d_out, int out_size, void* d_ws, size_t ws_size,
                              hipStream_t stream) {
    const float* inp = (const float*)d_in[0];
    const float* w = (const float*)d_in[1];
    float* outq = (float*)d_out;
    float* loss = outq + NQ;
    float* usage = outq + NQ + 1;
    float* wsq = (float*)d_ws;
    float* partial = wsq + KCODES;

    hipFuncSetAttribute((const void*)vq_main, hipFuncAttributeMaxDynamicSharedMemorySize,
                        SMEM_BYTES);

    init_kernel<<<4, 256, 0, stream>>>(usage);
    wsq_kernel<<<KCODES / 4, 256, 0, stream>>>(w, wsq);
    vq_main<<<512, 256, SMEM_BYTES, stream>>>(inp, w, wsq, outq, usage, partial);
    final_kernel<<<1, 256, 0, stream>>>(partial, loss);
}

// Round 2
// 119.581 us; speedup vs baseline: 3.2210x; 3.2210x over previous
//
#include <hip/hip_runtime.h>

// VQ-VAE forward via bf16-split MFMA GEMM.
// d_out layout: [0,8388608) quantized f32 | [8388608] loss | [8388609,+1024) usage
// d_out's quantized region doubles as the 32 MiB A-image staging buffer
// (written by conv_x, read by vq_gemm, overwritten by vq_gather).
// d_ws: [0,1MiB) B-image | [1MiB,+4KiB) wsq | then 2 MiB best_part | 1 KiB partials.

typedef __attribute__((ext_vector_type(8))) short bf16x8;
typedef __attribute__((ext_vector_type(4))) float f32x4;
typedef unsigned long long u64;
typedef unsigned int u32;

#define NQ 8388608

__device__ __forceinline__ ushort f2bf(float x) {
    u32 u = __float_as_uint(x);
    u32 r = (u + 0x7FFFu + ((u >> 16) & 1u)) >> 16;  // RNE
    return (ushort)r;
}

__device__ __forceinline__ uint4 pack8(const ushort* h) {
    uint4 v;
    v.x = (u32)h[0] | ((u32)h[1] << 16);
    v.y = (u32)h[2] | ((u32)h[3] << 16);
    v.z = (u32)h[4] | ((u32)h[5] << 16);
    v.w = (u32)h[6] | ((u32)h[7] << 16);
    return v;
}

__device__ __forceinline__ u32 sortkey(float f) {
    u32 u = __float_as_uint(f);
    return (u & 0x80000000u) ? ~u : (u | 0x80000000u);
}

// ---- weight -> B image (wh tiles 0-7, wl tiles 8-15 per nb) + usage zero ----
extern "C" __global__ __launch_bounds__(256) void conv_w(const float* __restrict__ w,
                                                         char* __restrict__ Bimg,
                                                         float* __restrict__ usage) {
    int gid = blockIdx.x * 256 + threadIdx.x;  // 32768 = 1024 n x 32 dc
    if (gid < 1024) usage[gid] = 0.0f;
    int n = gid & 1023, dc = gid >> 10;
    const float* src = w + n * 256 + dc * 8;
    float4 v0 = *(const float4*)src;
    float4 v1 = *(const float4*)(src + 4);
    float xs[8] = {v0.x, v0.y, v0.z, v0.w, v1.x, v1.y, v1.z, v1.w};
    ushort h[8], l[8];
    #pragma unroll
    for (int j = 0; j < 8; ++j) {
        ushort hh = f2bf(xs[j]);
        h[j] = hh;
        l[j] = f2bf(xs[j] - __uint_as_float((u32)hh << 16));
    }
    int nb = n >> 7, nrow = n & 127;
    int ti = dc >> 2, c = dc & 3;
    size_t off = ((size_t)(nb * 16 + ti)) * 8192 + (size_t)c * 2048 + (size_t)nrow * 16;
    *(uint4*)(Bimg + off) = pack8(h);
    *(uint4*)(Bimg + off + 8 * 8192) = pack8(l);
}

// ---- wsq[k] = sum_d w[k][d]^2 (one wave per row) ----
extern "C" __global__ __launch_bounds__(256) void wsq_kernel(const float* __restrict__ w,
                                                             float* __restrict__ wsq) {
    int wave = threadIdx.x >> 6, lane = threadIdx.x & 63;
    int k = blockIdx.x * 4 + wave;
    float4 v = *reinterpret_cast<const float4*>(w + (size_t)k * 256 + lane * 4);
    float s = v.x * v.x + v.y * v.y + v.z * v.z + v.w * v.w;
    #pragma unroll
    for (int off = 32; off >= 1; off >>= 1) s += __shfl_xor(s, off, 64);
    if (lane == 0) wsq[k] = s;
}

// ---- input transpose+convert -> A image (xh tiles 0-7, xl tiles 8-15 per mb) ----
extern "C" __global__ __launch_bounds__(256) void conv_x(const float* __restrict__ inp,
                                                         char* __restrict__ Aimg) {
    __shared__ float xt[64 * 132];
    int blk = blockIdx.x;  // 1024 = mb*4 + dq
    int mb = blk >> 2, dq = blk & 3;
    int b = mb >> 3, hw0 = (mb & 7) * 128, d0 = dq * 64;
    int t = threadIdx.x;
    const float* base = inp + (size_t)b * 262144 + (size_t)d0 * 1024 + hw0;
    #pragma unroll
    for (int it = 0; it < 8; ++it) {
        int e = it * 256 + t;
        int d = e >> 5, hw4 = e & 31;
        float4 v = *(const float4*)(base + (size_t)d * 1024 + hw4 * 4);
        *(float4*)(xt + d * 132 + hw4 * 4) = v;
    }
    __syncthreads();
    int hw = t & 127, dh = t >> 7;
    size_t tilebase = (size_t)mb * 16 * 8192;
    #pragma unroll
    for (int it = 0; it < 4; ++it) {
        int dc = it * 2 + dh;  // 0..7 (8 d's each)
        ushort h[8], l[8];
        #pragma unroll
        for (int j = 0; j < 8; ++j) {
            float x = xt[(dc * 8 + j) * 132 + hw];
            ushort hh = f2bf(x);
            h[j] = hh;
            l[j] = f2bf(x - __uint_as_float((u32)hh << 16));
        }
        int ti = dq * 2 + (dc >> 2), c = dc & 3;
        size_t off = tilebase + (size_t)ti * 8192 + (size_t)c * 2048 + (size_t)hw * 16;
        *(uint4*)(Aimg + off) = pack8(h);
        *(uint4*)(Aimg + off + 8 * 8192) = pack8(l);
    }
}

// ---- MFMA GEMM (K_eff = 768: xh.wh + xh.wl + xl.wh) + fused argmin ----
extern "C" __global__ __launch_bounds__(256) void vq_gemm(const char* __restrict__ Aimg,
                                                          const char* __restrict__ Bimg,
                                                          const float* __restrict__ wsq,
                                                          u64* __restrict__ best_part) {
    __shared__ __align__(16) char smem[32768];  // 2 bufs x (A 8KB + B 8KB)
    int tid = threadIdx.x, lane = tid & 63, wv = tid >> 6;
    int bid = blockIdx.x;
    int lb = (bid & 7) * 256 + (bid >> 3);  // XCD-chunked swizzle (2048 % 8 == 0)
    int mb = lb >> 3, nb = lb & 7;
    int wm = wv >> 1, wn = wv & 1;
    int rm = wm * 64, cn = wn * 64;
    int cg = lane >> 4, rl = lane & 15;

    f32x4 acc[4][4];
    #pragma unroll
    for (int i = 0; i < 4; ++i)
        #pragma unroll
        for (int j = 0; j < 4; ++j) acc[i][j] = (f32x4){0.f, 0.f, 0.f, 0.f};

    const char* Abase = Aimg + (size_t)mb * 16 * 8192;
    const char* Bbase = Bimg + (size_t)nb * 16 * 8192;

    auto stage = [&](int kt, int buf) {
        int at = kt < 8 ? kt : kt - 8;    // 0-7:xh, 8-15:xh, 16-23:xl
        int bt = kt < 16 ? kt : kt - 16;  // 0-7:wh, 8-15:wl, 16-23:wh
        const char* ga = Abase + (size_t)at * 8192;
        const char* gb = Bbase + (size_t)bt * 8192;
        char* la = smem + buf * 16384;
        char* lbp = la + 8192;
        #pragma unroll
        for (int i = 0; i < 2; ++i) {
            int off = (wv + i * 4) * 1024 + lane * 16;
            __builtin_amdgcn_global_load_lds(
                (const __attribute__((address_space(1))) u32*)(ga + off),
                (__attribute__((address_space(3))) u32*)(la + off), 16, 0, 0);
            __builtin_amdgcn_global_load_lds(
                (const __attribute__((address_space(1))) u32*)(gb + off),
                (__attribute__((address_space(3))) u32*)(lbp + off), 16, 0, 0);
        }
    };

    stage(0, 0);
    __syncthreads();

    for (int kt = 0; kt < 24; ++kt) {
        int cur = kt & 1;
        if (kt < 23) stage(kt + 1, cur ^ 1);
        const char* Ab = smem + cur * 16384 + cg * 2048;
        const char* Bb = Ab + 8192;
        bf16x8 af[4], bf[4];
        #pragma unroll
        for (int f = 0; f < 4; ++f) {
            af[f] = *(const bf16x8*)(Ab + (rm + f * 16 + rl) * 16);
            bf[f] = *(const bf16x8*)(Bb + (cn + f * 16 + rl) * 16);
        }
        #pragma unroll
        for (int fi = 0; fi < 4; ++fi)
            #pragma unroll
            for (int fj = 0; fj < 4; ++fj)
                acc[fi][fj] = __builtin_amdgcn_mfma_f32_16x16x32_bf16(af[fi], bf[fj],
                                                                     acc[fi][fj], 0, 0, 0);
        __syncthreads();
    }

    // distances s = wsq[n] - 2*dot; per-lane min over fj, butterfly over 16 col-lanes
    float wq[4];
    #pragma unroll
    for (int fj = 0; fj < 4; ++fj) wq[fj] = wsq[nb * 128 + cn + fj * 16 + rl];

    u64* red = (u64*)smem;  // [128][2] reuse
    #pragma unroll
    for (int fi = 0; fi < 4; ++fi) {
        #pragma unroll
        for (int r = 0; r < 4; ++r) {
            int mloc = rm + fi * 16 + cg * 4 + r;
            u64 p = ~0ull;
            #pragma unroll
            for (int fj = 0; fj < 4; ++fj) {
                float dist = wq[fj] - 2.0f * acc[fi][fj][r];
                u32 nidx = (u32)(nb * 128 + cn + fj * 16 + rl);
                u64 cand = ((u64)sortkey(dist) << 32) | nidx;  // tie -> lowest n
                p = cand < p ? cand : p;
            }
            #pragma unroll
            for (int m2 = 1; m2 <= 8; m2 <<= 1) {
                u64 q = __shfl_xor(p, m2, 64);
                p = q < p ? q : p;
            }
            if (rl == 0) red[mloc * 2 + wn] = p;
        }
    }
    __syncthreads();
    if (tid < 128) {
        u64 a = red[tid * 2], b2 = red[tid * 2 + 1];
        u64 mn = a < b2 ? a : b2;
        best_part[((size_t)mb * 128 + tid) * 8 + nb] = mn;
    }
}

// ---- final argmin over 8 nb partials, gather codes, write output, loss, usage ----
extern "C" __global__ __launch_bounds__(256) void vq_gather(const float* __restrict__ inp,
                                                            const float* __restrict__ w,
                                                            const u64* __restrict__ best_part,
                                                            float* __restrict__ outq,
                                                            float* __restrict__ usage,
                                                            float* __restrict__ partial) {
    __shared__ int s_idx[128];
    __shared__ float wred[4];
    int mb = blockIdx.x, t = threadIdx.x;
    int b = mb >> 3, hw0 = (mb & 7) * 128;
    if (t < 128) {
        const u64* p = best_part + ((size_t)mb * 128 + t) * 8;
        u64 mn = p[0];
        #pragma unroll
        for (int j = 1; j < 8; ++j) { u64 v = p[j]; mn = v < mn ? v : mn; }
        int idx = (int)(mn & 1023u);
        s_idx[t] = idx;
        atomicAdd(usage + idx, 1.0f);  // integer-valued f32: exact, order-independent
    }
    __syncthreads();
    int i = t & 127, dg = t >> 7;
    const float* xb = inp + (size_t)b * 262144 + hw0 + i;
    float* ob = outq + (size_t)b * 262144 + hw0 + i;
    const float* wrow = w + (size_t)s_idx[i] * 256;
    float lsum = 0.0f;
    #pragma unroll 4
    for (int it = 0; it < 32; ++it) {
        int d0 = dg * 128 + it * 4;
        float4 q = *(const float4*)(wrow + d0);
        float qa[4] = {q.x, q.y, q.z, q.w};
        #pragma unroll
        for (int j = 0; j < 4; ++j) {
            size_t o = (size_t)(d0 + j) * 1024;
            float x = xb[o];
            ob[o] = qa[j];
            float df = qa[j] - x;
            lsum += df * df;
        }
    }
    #pragma unroll
    for (int off = 32; off >= 1; off >>= 1) lsum += __shfl_xor(lsum, off, 64);
    if ((t & 63) == 0) wred[t >> 6] = lsum;
    __syncthreads();
    if (t == 0) partial[mb] = (wred[0] + wred[1]) + (wred[2] + wred[3]);
}

extern "C" __global__ __launch_bounds__(256) void vq_final(const float* __restrict__ partial,
                                                           float* __restrict__ loss) {
    __shared__ float sm[256];
    int t = threadIdx.x;
    sm[t] = partial[t];
    __syncthreads();
    #pragma unroll
    for (int off = 128; off >= 1; off >>= 1) {
        if (t < off) sm[t] += sm[t + off];
        __syncthreads();
    }
    if (t == 0) loss[0] = sm[0] * (1.25f / 8388608.0f);
}

extern "C" void kernel_launch(void* const* d_in, const int* in_sizes, int n_in,
                              void* d_out, int out_size, void* d_ws, size_t ws_size,
                              hipStream_t stream) {
    const float* inp = (const float*)d_in[0];
    const float* w = (const float*)d_in[1];
    float* outq = (float*)d_out;
    float* loss = outq + NQ;
    float* usage = outq + NQ + 1;

    char* Aimg = (char*)d_out;  // 32 MiB staging, overwritten by vq_gather
    char* ws = (char*)d_ws;
    char* Bimg = ws;                                        // 1 MiB
    float* wsq = (float*)(ws + (1 << 20));                  // 4 KiB
    u64* best_part = (u64*)(ws + (1 << 20) + 4096);         // 2 MiB
    float* partial = (float*)(ws + (1 << 20) + 4096 + 32768 * 8 * 8);  // 1 KiB

    conv_w<<<128, 256, 0, stream>>>(w, Bimg, usage);
    wsq_kernel<<<256, 256, 0, stream>>>(w, wsq);
    conv_x<<<1024, 256, 0, stream>>>(inp, Aimg);
    vq_gemm<<<2048, 256, 0, stream>>>(Aimg, Bimg, wsq, best_part);
    vq_gather<<<256, 256, 0, stream>>>(inp, w, best_part, outq, usage, partial);
    vq_final<<<1, 256, 0, stream>>>(partial, loss);
}

// Round 3
// 116.029 us; speedup vs baseline: 3.3196x; 1.0306x over previous
//
#include <hip/hip_runtime.h>

// VQ-VAE forward via bf16-split MFMA GEMM, 8-phase counted-vmcnt schedule.
// d_out layout: [0,8388608) quantized f32 | [8388608] loss | [8388609,+1024) usage
// d_out's quantized region doubles as the 32 MiB A-image (conv_x -> vq_gemm),
// overwritten by vq_gather (which no longer reads inputs: loss uses the
// distance identity sum((q-x)^2) = sum(xsq + (wsq - 2 x.w)) ).
// d_ws: [0,1MiB) B-image | +4KiB wsq | +128KiB xsq | +1MiB best_part | partials.

typedef __attribute__((ext_vector_type(8))) short bf16x8;
typedef __attribute__((ext_vector_type(4))) float f32x4;
typedef unsigned long long u64;
typedef unsigned int u32;

#define NQ 8388608
#define LDSB 65536  // bytes per K-tile buffer: A 32KB + B 32KB

__device__ __forceinline__ ushort f2bf(float x) {
    u32 u = __float_as_uint(x);
    u32 r = (u + 0x7FFFu + ((u >> 16) & 1u)) >> 16;  // RNE
    return (ushort)r;
}
__device__ __forceinline__ float bf2f(ushort h) { return __uint_as_float((u32)h << 16); }

__device__ __forceinline__ uint4 pack8(const ushort* h) {
    uint4 v;
    v.x = (u32)h[0] | ((u32)h[1] << 16);
    v.y = (u32)h[2] | ((u32)h[3] << 16);
    v.z = (u32)h[4] | ((u32)h[5] << 16);
    v.w = (u32)h[6] | ((u32)h[7] << 16);
    return v;
}

__device__ __forceinline__ u32 sortkey(float f) {
    u32 u = __float_as_uint(f);
    return (u & 0x80000000u) ? ~u : (u | 0x80000000u);
}

// ---- weight -> B image [nb][TB 0..7][s][cg][col][16B] (TB 0-3 wh, 4-7 wl)
//      + wsq + usage zero (fused) ----
extern "C" __global__ __launch_bounds__(256) void conv_w(const float* __restrict__ w,
                                                         char* __restrict__ Bimg,
                                                         float* __restrict__ wsq,
                                                         float* __restrict__ usage) {
    int gid = blockIdx.x * 256 + threadIdx.x;  // 32768 = 1024 n x 32 dc
    int n = gid >> 5, dc = gid & 31;
    const float* src = w + n * 256 + dc * 8;
    float4 v0 = *(const float4*)src;
    float4 v1 = *(const float4*)(src + 4);
    float xs[8] = {v0.x, v0.y, v0.z, v0.w, v1.x, v1.y, v1.z, v1.w};
    ushort h[8], l[8];
    float sq = 0.0f;
    #pragma unroll
    for (int j = 0; j < 8; ++j) {
        ushort hh = f2bf(xs[j]);
        h[j] = hh;
        l[j] = f2bf(xs[j] - bf2f(hh));
        sq += xs[j] * xs[j];
    }
    int nb = n >> 8, col = n & 255;
    size_t off = (size_t)nb * 262144 + (size_t)(dc >> 3) * 32768 +
                 (size_t)((dc >> 2) & 1) * 16384 + (size_t)(dc & 3) * 4096 + (size_t)col * 16;
    *(uint4*)(Bimg + off) = pack8(h);
    *(uint4*)(Bimg + off + 131072) = pack8(l);
    #pragma unroll
    for (int m = 1; m <= 16; m <<= 1) sq += __shfl_xor(sq, m, 64);
    if ((threadIdx.x & 31) == 0) { wsq[n] = sq; usage[n] = 0.0f; }
}

// ---- input -> A image [mb][TA 0..7][s][cg][row][16B] (TA 0-3 xh, 4-7 xl) + xsq ----
extern "C" __global__ __launch_bounds__(256) void conv_x(const float* __restrict__ inp,
                                                         char* __restrict__ Aimg,
                                                         float* __restrict__ xsq) {
    __shared__ float xt[64 * 128];
    __shared__ float sq2[256];
    int blk = blockIdx.x;  // 256 = mb*2 + rh
    int mb = blk >> 1, rh = blk & 1;
    int b = mb >> 2, hw0 = (mb & 3) * 256 + rh * 128;
    int tid = threadIdx.x;
    const float* base = inp + (size_t)b * 262144 + hw0;
    char* Ab = Aimg + (size_t)mb * 262144;
    int r = tid & 127, gh = tid >> 7;
    float xsql = 0.0f;
    for (int dcb = 0; dcb < 4; ++dcb) {
        __syncthreads();
        #pragma unroll
        for (int it = 0; it < 8; ++it) {
            int e = it * 256 + tid;  // 2048 float4
            int dd = e >> 5, h4 = e & 31;
            float4 v = *(const float4*)(base + (size_t)(dcb * 64 + dd) * 1024 + h4 * 4);
            *(float4*)(xt + dd * 128 + h4 * 4) = v;
        }
        __syncthreads();
        #pragma unroll
        for (int gg = 0; gg < 4; ++gg) {
            int g = gh * 4 + gg;  // 0..7
            ushort h[8], l[8];
            #pragma unroll
            for (int j = 0; j < 8; ++j) {
                float x = xt[(g * 8 + j) * 128 + r];
                ushort hh = f2bf(x);
                h[j] = hh;
                l[j] = f2bf(x - bf2f(hh));
                xsql += x * x;
            }
            size_t off = (size_t)dcb * 32768 + (size_t)(g >> 2) * 16384 +
                         (size_t)(g & 3) * 4096 + (size_t)(rh * 128 + r) * 16;
            *(uint4*)(Ab + off) = pack8(h);
            *(uint4*)(Ab + off + 131072) = pack8(l);
        }
    }
    sq2[gh * 128 + r] = xsql;
    __syncthreads();
    if (tid < 128) xsq[(size_t)mb * 256 + rh * 128 + tid] = sq2[tid] + sq2[128 + tid];
}

// ---- 256x256 8-phase MFMA GEMM (K_eff=768) + fused argmin ----
extern "C" __global__ __launch_bounds__(512, 2) void vq_gemm(const char* __restrict__ Aimg,
                                                             const char* __restrict__ Bimg,
                                                             const float* __restrict__ wsq,
                                                             u64* __restrict__ best_part) {
    extern __shared__ char lds[];  // 131072 = 2 x LDSB
    const int tid = threadIdx.x, lane = tid & 63, wv = tid >> 6;
    const int wm = wv >> 2, wn = wv & 3;
    const int cg = lane >> 4, rl = lane & 15;
    int bid = blockIdx.x;
    int lb = (bid & 7) * 64 + (bid >> 3);  // XCD-chunked swizzle (512 % 8 == 0)
    const int mb = lb >> 2, nb = lb & 3;

    const char* Ag = Aimg + (size_t)mb * 262144;
    const char* Bg = Bimg + (size_t)nb * 262144;

    f32x4 acc[8][4];
    #pragma unroll
    for (int i = 0; i < 8; ++i)
        #pragma unroll
        for (int j = 0; j < 4; ++j) acc[i][j] = (f32x4){0.f, 0.f, 0.f, 0.f};

// stage unit u: 0=A s0, 1=B s0, 2=A s1, 3=B s1 of K-tile T_ into buf (T_&1). 2 loads.
#define STAGE(T_, u_)                                                                        \
    do {                                                                                     \
        int Tc = (T_) > 11 ? 11 : (T_);                                                      \
        int s_ = ((u_) >> 1) & 1;                                                            \
        const char* g_;                                                                      \
        char* l_;                                                                            \
        if ((u_) & 1) {                                                                      \
            g_ = Bg + (size_t)(Tc < 8 ? Tc : Tc - 8) * 32768 + s_ * 16384;                   \
            l_ = lds + ((T_)&1) * LDSB + 32768 + s_ * 16384;                                 \
        } else {                                                                             \
            g_ = Ag + (size_t)(Tc < 8 ? (Tc & 3) : Tc - 4) * 32768 + s_ * 16384;             \
            l_ = lds + ((T_)&1) * LDSB + s_ * 16384;                                         \
        }                                                                                    \
        __builtin_amdgcn_global_load_lds(                                                    \
            (const __attribute__((address_space(1))) u32*)(g_ + tid * 16),                   \
            (__attribute__((address_space(3))) u32*)(l_ + tid * 16), 16, 0, 0);              \
        __builtin_amdgcn_global_load_lds(                                                    \
            (const __attribute__((address_space(1))) u32*)(g_ + tid * 16 + 8192),            \
            (__attribute__((address_space(3))) u32*)(l_ + tid * 16 + 8192), 16, 0, 0);       \
    } while (0)

// one phase: frag ds_reads | stage issue | barrier | lgkm drain | 16 MFMA | [vmcnt] barrier
#define PHASE(buf_, s_, half_, loadB_, stT_, stU_, vm_)                                      \
    do {                                                                                     \
        const char* Abp = lds + (buf_)*LDSB + (s_)*16384 + cg * 4096;                        \
        const char* Bbp = lds + (buf_)*LDSB + 32768 + (s_)*16384 + cg * 4096;                \
        if (loadB_) {                                                                        \
            _Pragma("unroll") for (int fn = 0; fn < 4; ++fn)                                 \
                bfr[fn] = *(const bf16x8*)(Bbp + (wn * 64 + fn * 16 + rl) * 16);             \
        }                                                                                    \
        bf16x8 afr[4];                                                                       \
        _Pragma("unroll") for (int f = 0; f < 4; ++f)                                        \
            afr[f] = *(const bf16x8*)(Abp + (wm * 128 + (half_)*64 + f * 16 + rl) * 16);     \
        STAGE(stT_, stU_);                                                                   \
        __builtin_amdgcn_sched_barrier(0);                                                   \
        __builtin_amdgcn_s_barrier();                                                        \
        asm volatile("s_waitcnt lgkmcnt(0)" ::: "memory");                                   \
        __builtin_amdgcn_sched_barrier(0);                                                   \
        __builtin_amdgcn_s_setprio(1);                                                       \
        _Pragma("unroll") for (int f = 0; f < 4; ++f)                                        \
            _Pragma("unroll") for (int fn = 0; fn < 4; ++fn)                                 \
                acc[(half_)*4 + f][fn] = __builtin_amdgcn_mfma_f32_16x16x32_bf16(            \
                    afr[f], bfr[fn], acc[(half_)*4 + f][fn], 0, 0, 0);                       \
        __builtin_amdgcn_s_setprio(0);                                                       \
        __builtin_amdgcn_sched_barrier(0);                                                   \
        if (vm_) asm volatile("s_waitcnt vmcnt(4)" ::: "memory");                            \
        __builtin_amdgcn_s_barrier();                                                        \
    } while (0)

    // prologue: T0 fully + T1 s0 units (12 loads), drain T0, rendezvous
    STAGE(0, 0); STAGE(0, 1); STAGE(0, 2); STAGE(0, 3);
    STAGE(1, 0); STAGE(1, 1);
    asm volatile("s_waitcnt vmcnt(4)" ::: "memory");
    __builtin_amdgcn_s_barrier();

    bf16x8 bfr[4];
    for (int j = 0; j < 6; ++j) {
        int T0 = 2 * j;
        PHASE(0, 0, 0, 1, T0 + 1, 2, 0);  // ph1: stage T1.A1
        PHASE(0, 0, 1, 0, T0 + 1, 3, 0);  // ph2: stage T1.B1
        PHASE(0, 1, 0, 1, T0 + 2, 0, 0);  // ph3: stage T2.A0
        PHASE(0, 1, 1, 0, T0 + 2, 1, 1);  // ph4: stage T2.B0, vmcnt(4)
        PHASE(1, 0, 0, 1, T0 + 2, 2, 0);  // ph5: stage T2.A1
        PHASE(1, 0, 1, 0, T0 + 2, 3, 0);  // ph6: stage T2.B1
        PHASE(1, 1, 0, 1, T0 + 3, 0, 0);  // ph7: stage T3.A0
        PHASE(1, 1, 1, 0, T0 + 3, 1, 1);  // ph8: stage T3.B0, vmcnt(4)
    }

    // ---- epilogue: drain all staging, then argmin reduce in LDS ----
    asm volatile("s_waitcnt vmcnt(0)" ::: "memory");
    __builtin_amdgcn_s_barrier();

    float wq[4];
    #pragma unroll
    for (int fn = 0; fn < 4; ++fn) wq[fn] = wsq[nb * 256 + wn * 64 + fn * 16 + rl];

    u64* red = (u64*)lds;  // [256][4]
    #pragma unroll
    for (int fm = 0; fm < 8; ++fm) {
        #pragma unroll
        for (int r = 0; r < 4; ++r) {
            u64 p = ~0ull;
            #pragma unroll
            for (int fn = 0; fn < 4; ++fn) {
                float dist = wq[fn] - 2.0f * acc[fm][fn][r];
                u32 nidx = (u32)(nb * 256 + wn * 64 + fn * 16 + rl);
                u64 cand = ((u64)sortkey(dist) << 32) | nidx;  // tie -> lowest n
                p = cand < p ? cand : p;
            }
            #pragma unroll
            for (int m2 = 1; m2 <= 8; m2 <<= 1) {
                u64 q = __shfl_xor(p, m2, 64);
                p = q < p ? q : p;
            }
            if (rl == 0) red[(wm * 128 + fm * 16 + cg * 4 + r) * 4 + wn] = p;
        }
    }
    __syncthreads();
    if (tid < 256) {
        const u64* rp = red + tid * 4;
        u64 mn = rp[0];
        #pragma unroll
        for (int q2 = 1; q2 < 4; ++q2) { u64 v = rp[q2]; mn = v < mn ? v : mn; }
        best_part[((size_t)mb * 256 + tid) * 4 + nb] = mn;
    }
#undef PHASE
#undef STAGE
}

// ---- min over 4 nb partials, gather codes, write out, loss via identity, usage ----
extern "C" __global__ __launch_bounds__(256) void vq_gather(const float* __restrict__ w,
                                                            const u64* __restrict__ best_part,
                                                            const float* __restrict__ xsq,
                                                            float* __restrict__ outq,
                                                            float* __restrict__ usage,
                                                            float* __restrict__ partial) {
    __shared__ int sidx[128];
    __shared__ float sred[4];
    int pb = blockIdx.x;  // 128 points each
    int p0 = pb * 128;
    int b = p0 >> 10, hw0 = p0 & 1023;
    int t = threadIdx.x;
    float lsum = 0.0f;
    if (t < 128) {
        const u64* pp = best_part + (size_t)(p0 + t) * 4;
        u64 mn = pp[0];
        #pragma unroll
        for (int j = 1; j < 4; ++j) { u64 v = pp[j]; mn = v < mn ? v : mn; }
        int idx = (int)(mn & 0xFFFFFFFFull);
        sidx[t] = idx;
        atomicAdd(usage + idx, 1.0f);  // integer-valued f32: exact, order-independent
        u32 k = (u32)(mn >> 32);
        float dv = (k & 0x80000000u) ? __uint_as_float(k & 0x7FFFFFFFu)
                                     : __uint_as_float(~k);
        lsum = xsq[p0 + t] + dv;  // ||x||^2 + (||w||^2 - 2 x.w) = ||x - w||^2
    }
    __syncthreads();
    int pi = t & 127, dh = t >> 7;
    float* ob = outq + (size_t)b * 262144 + hw0 + pi;
    const float* wrow = w + (size_t)sidx[pi] * 256;
    #pragma unroll 4
    for (int d4 = 0; d4 < 32; ++d4) {
        int d = dh * 128 + d4 * 4;
        float4 q = *(const float4*)(wrow + d);
        ob[(size_t)d * 1024] = q.x;
        ob[(size_t)(d + 1) * 1024] = q.y;
        ob[(size_t)(d + 2) * 1024] = q.z;
        ob[(size_t)(d + 3) * 1024] = q.w;
    }
    #pragma unroll
    for (int off = 32; off >= 1; off >>= 1) lsum += __shfl_xor(lsum, off, 64);
    if ((t & 63) == 0) sred[t >> 6] = lsum;
    __syncthreads();
    if (t == 0) partial[pb] = (sred[0] + sred[1]) + (sred[2] + sred[3]);
}

extern "C" __global__ __launch_bounds__(256) void vq_final(const float* __restrict__ partial,
                                                           float* __restrict__ loss) {
    __shared__ float sm[256];
    int t = threadIdx.x;
    sm[t] = partial[t];
    __syncthreads();
    #pragma unroll
    for (int off = 128; off >= 1; off >>= 1) {
        if (t < off) sm[t] += sm[t + off];
        __syncthreads();
    }
    if (t == 0) loss[0] = sm[0] * (1.25f / 8388608.0f);
}

extern "C" void kernel_launch(void* const* d_in, const int* in_sizes, int n_in,
                              void* d_out, int out_size, void* d_ws, size_t ws_size,
                              hipStream_t stream) {
    const float* inp = (const float*)d_in[0];
    const float* w = (const float*)d_in[1];
    float* outq = (float*)d_out;
    float* loss = outq + NQ;
    float* usage = outq + NQ + 1;

    char* Aimg = (char*)d_out;  // 32 MiB staging, overwritten by vq_gather
    char* ws = (char*)d_ws;
    char* Bimg = ws;                                            // 1 MiB
    float* wsq = (float*)(ws + (1 << 20));                      // 4 KiB
    float* xsq = (float*)(ws + (1 << 20) + 4096);               // 128 KiB
    u64* best_part = (u64*)(ws + (1 << 20) + 4096 + 131072);    // 1 MiB
    float* partial = (float*)(ws + (2 << 20) + 4096 + 131072);  // 1 KiB

    hipFuncSetAttribute((const void*)vq_gemm, hipFuncAttributeMaxDynamicSharedMemorySize,
                        131072);

    conv_w<<<128, 256, 0, stream>>>(w, Bimg, wsq, usage);
    conv_x<<<256, 256, 0, stream>>>(inp, Aimg, xsq);
    vq_gemm<<<512, 512, 131072, stream>>>(Aimg, Bimg, wsq, best_part);
    vq_gather<<<256, 256, 0, stream>>>(w, best_part, xsq, outq, usage, partial);
    vq_final<<<1, 256, 0, stream>>>(partial, loss);
}